// Round 1
// baseline (799.501 us; speedup 1.0000x reference)
//
#include <hip/hip_runtime.h>
#include <math.h>

#define B_      32
#define H_      2048
#define NH_     32
#define NKV_    8
#define HD_     64
#define G_      4        // NH/NKV
#define INTER_  8192
#define NBLK_   256
#define BS_     16
#define NCHUNK_ 8
#define CHUNK_  512      // tokens per attention chunk

// ---------------- ws layout (float offsets) ----------------
#define OFF_NORMED_T  0          // [H][B]        65536
#define OFF_QKV       65536      // [B][3072]     98304
#define OFF_QROPE     163840     // [B][NH*HD]    65536
#define OFF_X2        229376     // [B][H]        65536
#define OFF_HT        294912     // [H][B]        65536
#define OFF_ATTN_T    360448     // [NH*HD][B]    65536
#define OFF_G         425984     // [B][INTER]    262144
#define OFF_U         688128     // [B][INTER]    262144
#define OFF_ACT_T     950272     // [INTER][B]    262144
#define OFF_OPART     1212416    // [B][NKV][NCHUNK][G][HD]  524288
#define OFF_MPART     1736704    // [B][NKV][NCHUNK][G]      8192
#define OFF_LPART     1744896    // 8192
// total 1753088 floats = ~6.7 MB

// ---------------- init: x2 = x, zero qkv + g/u (atomic targets) ------------
__global__ __launch_bounds__(256) void init_kernel(const float* __restrict__ x,
                                                   float* __restrict__ x2,
                                                   float* __restrict__ qkv,
                                                   float* __restrict__ gu) {
    int idx = blockIdx.x * 256 + threadIdx.x;
    if (idx < 65536) x2[idx] = x[idx];
    int i2 = idx - 65536;
    if (i2 >= 0 && i2 < 98304) qkv[i2] = 0.f;
    int i3 = idx - 163840;
    if (i3 >= 0 && i3 < 524288) gu[i3] = 0.f;
}

// ---------------- RMSNorm: writes transposed [H][B]; optional copy of input -
__global__ __launch_bounds__(256) void rmsnorm_kernel(const float* __restrict__ xin,
                                                      const float* __restrict__ w,
                                                      float* __restrict__ out_t,
                                                      float* __restrict__ copyout) {
    int b = blockIdx.x, tid = threadIdx.x;
    const float* xr = xin + (size_t)b * H_;
    float xv[8];
    float ss = 0.f;
#pragma unroll
    for (int j = 0; j < 8; ++j) {
        xv[j] = xr[tid + j * 256];
        ss += xv[j] * xv[j];
    }
#pragma unroll
    for (int off = 32; off >= 1; off >>= 1) ss += __shfl_xor(ss, off, 64);
    __shared__ float red[4];
    __shared__ float rbc;
    if ((tid & 63) == 0) red[tid >> 6] = ss;
    __syncthreads();
    if (tid == 0) rbc = rsqrtf((red[0] + red[1] + red[2] + red[3]) / (float)H_ + 1e-5f);
    __syncthreads();
    float r = rbc;
#pragma unroll
    for (int j = 0; j < 8; ++j) {
        int i = tid + j * 256;
        out_t[(size_t)i * B_ + b] = xv[j] * r * w[i];
        if (copyout) copyout[(size_t)b * H_ + i] = xv[j];
    }
}

// ---------------- generic GEMV core --------------------------------------
// x stored transposed [K][B] so inner-batch loads are wave-uniform (s_load).
// Block: 256 threads = 64 cols x 4 k-splits (k-split == wave id so k stays
// wave-uniform). Cross-block K split via gridDim.y -> atomicAdd epilogue.
__device__ __forceinline__ void gemv_block(const float* __restrict__ xt,
                                           const float* __restrict__ W, int Nw,
                                           int wcolbase, int krange,
                                           float* __restrict__ out, int Nout,
                                           int outcolbase, bool atomic_out) {
    int tid = threadIdx.x;
    int ct  = tid & 63;
    int ks  = __builtin_amdgcn_readfirstlane(tid >> 6);  // wave-uniform
    int rows = krange >> 2;
    int kb0 = blockIdx.y * krange + ks * rows;
    int wcol = wcolbase + ct;

    float acc[B_];
#pragma unroll
    for (int b = 0; b < B_; ++b) acc[b] = 0.f;

    const float* Wp  = W + (size_t)kb0 * Nw + wcol;
    const float* xp0 = xt + (size_t)kb0 * B_;
#pragma unroll 4
    for (int k = 0; k < rows; ++k) {
        float wv = Wp[(size_t)k * Nw];
        const float* xp = xp0 + k * B_;   // uniform address -> scalar loads
#pragma unroll
        for (int b = 0; b < B_; ++b) acc[b] = fmaf(xp[b], wv, acc[b]);
    }

    // reduce 4 k-splits via LDS, 8 batches per round
    __shared__ float red[2080];  // (ks*8+bb)*65 + ct
#pragma unroll
    for (int b0 = 0; b0 < B_; b0 += 8) {
#pragma unroll
        for (int bb = 0; bb < 8; ++bb) red[(ks * 8 + bb) * 65 + ct] = acc[b0 + bb];
        __syncthreads();
        for (int p = tid; p < 512; p += 256) {
            int bb = p >> 6, c2 = p & 63;
            float s = red[bb * 65 + c2] + red[(8 + bb) * 65 + c2] +
                      red[(16 + bb) * 65 + c2] + red[(24 + bb) * 65 + c2];
            float* op = out + (size_t)(b0 + bb) * Nout + outcolbase + c2;
            if (atomic_out) atomicAdd(op, s); else *op = s;
        }
        __syncthreads();
    }
}

// qkv fused: cols 0..2047 q, 2048..2559 k, 2560..3071 v.  grid(48,4)
__global__ __launch_bounds__(256) void gemv_qkv_kernel(const float* __restrict__ xt,
                                                       const float* __restrict__ qw,
                                                       const float* __restrict__ kw,
                                                       const float* __restrict__ vw,
                                                       float* __restrict__ qkv) {
    int cb = blockIdx.x;
    const float* W; int Nw, wbase;
    if (cb < 32)      { W = qw; Nw = 2048; wbase = cb << 6; }
    else if (cb < 40) { W = kw; Nw = 512;  wbase = (cb - 32) << 6; }
    else              { W = vw; Nw = 512;  wbase = (cb - 40) << 6; }
    gemv_block(xt, W, Nw, wbase, 512, qkv, 3072, cb << 6, true);
}

// o-proj: grid(32,8), atomic into x2 (pre-initialized with x -> residual)
__global__ __launch_bounds__(256) void gemv_o_kernel(const float* __restrict__ xt,
                                                     const float* __restrict__ W,
                                                     float* __restrict__ x2) {
    gemv_block(xt, W, 2048, blockIdx.x << 6, 256, x2, 2048, blockIdx.x << 6, true);
}

// gate+up fused: grid(256,2), atomic into zero-initialized g/u
__global__ __launch_bounds__(256) void gemv_gateup_kernel(const float* __restrict__ xt,
                                                          const float* __restrict__ gw,
                                                          const float* __restrict__ uw,
                                                          float* __restrict__ g,
                                                          float* __restrict__ u) {
    int cb = blockIdx.x;
    const float* W; float* out; int wbase;
    if (cb < 128) { W = gw; out = g; wbase = cb << 6; }
    else          { W = uw; out = u; wbase = (cb - 128) << 6; }
    gemv_block(xt, W, 8192, wbase, 1024, out, 8192, wbase, true);
}

// down-proj: grid(32,8), atomic into d_out (pre-initialized with x2 -> residual)
__global__ __launch_bounds__(256) void gemv_down_kernel(const float* __restrict__ xt,
                                                        const float* __restrict__ W,
                                                        float* __restrict__ dout) {
    gemv_block(xt, W, 2048, blockIdx.x << 6, 1024, dout, 2048, blockIdx.x << 6, true);
}

// ---------------- RoPE + paged cache write --------------------------------
__global__ __launch_bounds__(256) void rope_cache_kernel(const float* __restrict__ qkv,
                                                         const int* __restrict__ btab,
                                                         const int* __restrict__ seqlens,
                                                         float* __restrict__ qrope,
                                                         float* __restrict__ kc,
                                                         float* __restrict__ vc) {
    int b = blockIdx.x, tid = threadIdx.x;
    int pos = seqlens[b];
    const float* qkvb = qkv + (size_t)b * 3072;
    const float LOG2T = 13.287712379549449f;  // log2(10000)
    float fpos = (float)pos;
#pragma unroll
    for (int j = 0; j < 8; ++j) {
        int i = tid + j * 256;
        int d = i & 63, ii = d & 31;
        float ang = fpos * exp2f(-(float)(2 * ii) * (LOG2T / 64.f));
        float c = cosf(ang), s = sinf(ang);
        float v1 = qkvb[i];
        float v2 = qkvb[(d < 32) ? i + 32 : i - 32];
        qrope[(size_t)b * 2048 + i] = (d < 32) ? (v1 * c - v2 * s) : (v1 * c + v2 * s);
    }
    int blk = btab[b * NBLK_ + (pos >> 4)];
    size_t cbase = (size_t)(blk * BS_ + (pos & 15)) * NKV_ * HD_;
    for (int i = tid; i < NKV_ * HD_; i += 256) {
        int d = i & 63, ii = d & 31;
        float ang = fpos * exp2f(-(float)(2 * ii) * (LOG2T / 64.f));
        float c = cosf(ang), s = sinf(ang);
        float v1 = qkvb[2048 + i];
        float v2 = qkvb[2048 + ((d < 32) ? i + 32 : i - 32)];
        kc[cbase + i] = (d < 32) ? (v1 * c - v2 * s) : (v1 * c + v2 * s);
        vc[cbase + i] = qkvb[2560 + i];
    }
}

// ---------------- flash-decode attention: one chunk of 512 tokens ----------
// grid (NCHUNK, NKV, B), 256 threads.
__global__ __launch_bounds__(256) void attn_chunk_kernel(const float* __restrict__ qrope,
                                                         const float* __restrict__ kc,
                                                         const float* __restrict__ vc,
                                                         const int* __restrict__ btab,
                                                         const int* __restrict__ seqlens,
                                                         float* __restrict__ opart,
                                                         float* __restrict__ mpart,
                                                         float* __restrict__ lpart) {
    int cx = blockIdx.x, kv = blockIdx.y, b = blockIdx.z;
    int tid = threadIdx.x;
    int pos = seqlens[b];
    int c0 = cx * CHUNK_;
    int pidx = ((b * NKV_ + kv) * NCHUNK_ + cx) * G_;
    if (c0 > pos) {  // whole chunk beyond sequence
        if (tid < G_) { mpart[pidx + tid] = -__builtin_inff(); lpart[pidx + tid] = 0.f; }
        return;
    }
    __shared__ float qlds[G_][HD_];
    __shared__ float slds[G_][CHUNK_];
    {
        int h = tid >> 6, d = tid & 63;
        qlds[h][d] = qrope[((size_t)b * NH_ + kv * G_ + h) * HD_ + d] * 0.125f; // 1/sqrt(64)
    }
    __syncthreads();

    // pass 1: QK^T. 16 tokens at a time, 16 threads per token (float4 each).
    int grp = tid >> 4, ln = tid & 15;
    const int* bt = btab + b * NBLK_;
    for (int tb = 0; tb < CHUNK_; tb += 16) {
        int tl = tb + grp;
        int t = c0 + tl;
        int blk = bt[t >> 4];
        const float4 k4 = *(const float4*)(kc + ((size_t)(blk * BS_ + (t & 15)) * NKV_ + kv) * HD_ + ln * 4);
        bool valid = (t <= pos);
#pragma unroll
        for (int h = 0; h < G_; ++h) {
            const float4 q4 = *(const float4*)&qlds[h][ln * 4];
            float p = q4.x * k4.x + q4.y * k4.y + q4.z * k4.z + q4.w * k4.w;
#pragma unroll
            for (int off = 8; off >= 1; off >>= 1) p += __shfl_xor(p, off, 16);
            if (ln == 0) slds[h][tl] = valid ? p : -__builtin_inff();
        }
    }
    __syncthreads();

    // softmax per head: wave h handles head h
    int h = tid >> 6, lane = tid & 63;
    float m = -__builtin_inff();
    for (int i = lane; i < CHUNK_; i += 64) m = fmaxf(m, slds[h][i]);
#pragma unroll
    for (int off = 32; off >= 1; off >>= 1) m = fmaxf(m, __shfl_xor(m, off, 64));
    float l = 0.f;
    for (int i = lane; i < CHUNK_; i += 64) {
        float p = expf(slds[h][i] - m);
        slds[h][i] = p;
        l += p;
    }
#pragma unroll
    for (int off = 32; off >= 1; off >>= 1) l += __shfl_xor(l, off, 64);
    if (lane == 0) { mpart[pidx + h] = m; lpart[pidx + h] = l; }
    __syncthreads();

    // pass 2: P·V. thread = (head, dim)
    int d = lane;
    float o = 0.f;
    int tmax = min(CHUNK_, pos + 1 - c0);
    for (int tl = 0; tl < tmax; ++tl) {
        int t = c0 + tl;
        int blk = bt[t >> 4];
        o = fmaf(slds[h][tl], vc[((size_t)(blk * BS_ + (t & 15)) * NKV_ + kv) * HD_ + d], o);
    }
    opart[(size_t)(pidx + h) * HD_ + d] = o;
}

// ---------------- combine chunk partials (logsumexp) -----------------------
// grid (NH, B), 64 threads (one wave per query head)
__global__ __launch_bounds__(64) void attn_reduce_kernel(const float* __restrict__ opart,
                                                         const float* __restrict__ mpart,
                                                         const float* __restrict__ lpart,
                                                         float* __restrict__ attn_t) {
    int hq = blockIdx.x, b = blockIdx.y;
    int kv = hq >> 2, g = hq & 3;
    int lane = threadIdx.x;
    int base = ((b * NKV_ + kv) * NCHUNK_) * G_ + g;
    float mv[NCHUNK_], lv[NCHUNK_];
    float M = -__builtin_inff();
#pragma unroll
    for (int c = 0; c < NCHUNK_; ++c) {
        mv[c] = mpart[base + c * G_];
        lv[c] = lpart[base + c * G_];
        M = fmaxf(M, mv[c]);
    }
    float L = 0.f, o = 0.f;
#pragma unroll
    for (int c = 0; c < NCHUNK_; ++c) {
        if (lv[c] > 0.f) {
            float f = expf(mv[c] - M);
            L += lv[c] * f;
            o += f * opart[(size_t)(base + c * G_) * HD_ + lane];
        }
    }
    attn_t[(size_t)(hq * HD_ + lane) * B_ + b] = o / L;
}

// ---------------- silu(g)*u with LDS transpose -> act_t [INTER][B] ---------
__global__ __launch_bounds__(256) void silu_mul_kernel(const float* __restrict__ g,
                                                       const float* __restrict__ u,
                                                       float* __restrict__ act_t) {
    __shared__ float tile[8][33];
    int j0 = blockIdx.x * 8;
    int tid = threadIdx.x;
    int jj = tid & 7, b = tid >> 3;
    float gv = g[(size_t)b * INTER_ + j0 + jj];
    float uv = u[(size_t)b * INTER_ + j0 + jj];
    tile[jj][b] = (gv / (1.f + expf(-gv))) * uv;
    __syncthreads();
    int b2 = tid & 31, j2 = tid >> 5;
    act_t[(size_t)(j0 + j2) * B_ + b2] = tile[j2][b2];
}

// ---------------------------------------------------------------------------
extern "C" void kernel_launch(void* const* d_in, const int* in_sizes, int n_in,
                              void* d_out, int out_size, void* d_ws, size_t ws_size,
                              hipStream_t stream) {
    const float* x       = (const float*)d_in[0];
    float*       k_cache = (float*)d_in[1];   // restored from pristine each launch
    float*       v_cache = (float*)d_in[2];
    const float* ln1_w   = (const float*)d_in[3];
    const float* q_w     = (const float*)d_in[4];
    const float* k_w     = (const float*)d_in[5];
    const float* v_w     = (const float*)d_in[6];
    const float* o_w     = (const float*)d_in[7];
    const float* ln2_w   = (const float*)d_in[8];
    const float* gate_w  = (const float*)d_in[9];
    const float* up_w    = (const float*)d_in[10];
    const float* down_w  = (const float*)d_in[11];
    const int*   btab    = (const int*)d_in[12];
    const int*   seql    = (const int*)d_in[13];
    float* out = (float*)d_out;

    float* ws = (float*)d_ws;
    float* normed_t = ws + OFF_NORMED_T;
    float* qkv      = ws + OFF_QKV;
    float* qrope    = ws + OFF_QROPE;
    float* x2       = ws + OFF_X2;
    float* ht       = ws + OFF_HT;
    float* attn_t   = ws + OFF_ATTN_T;
    float* gbuf     = ws + OFF_G;
    float* ubuf     = ws + OFF_U;
    float* act_t    = ws + OFF_ACT_T;
    float* opart    = ws + OFF_OPART;
    float* mpart    = ws + OFF_MPART;
    float* lpart    = ws + OFF_LPART;

    init_kernel<<<2688, 256, 0, stream>>>(x, x2, qkv, gbuf /* g+u contiguous */);
    rmsnorm_kernel<<<32, 256, 0, stream>>>(x, ln1_w, normed_t, nullptr);
    gemv_qkv_kernel<<<dim3(48, 4), 256, 0, stream>>>(normed_t, q_w, k_w, v_w, qkv);
    rope_cache_kernel<<<32, 256, 0, stream>>>(qkv, btab, seql, qrope, k_cache, v_cache);
    attn_chunk_kernel<<<dim3(NCHUNK_, NKV_, B_), 256, 0, stream>>>(qrope, k_cache, v_cache,
                                                                   btab, seql, opart, mpart, lpart);
    attn_reduce_kernel<<<dim3(NH_, B_), 64, 0, stream>>>(opart, mpart, lpart, attn_t);
    gemv_o_kernel<<<dim3(32, 8), 256, 0, stream>>>(attn_t, o_w, x2);
    rmsnorm_kernel<<<32, 256, 0, stream>>>(x2, ln2_w, ht, out);  // also d_out = x2
    gemv_gateup_kernel<<<dim3(256, 2), 256, 0, stream>>>(ht, gate_w, up_w, gbuf, ubuf);
    silu_mul_kernel<<<1024, 256, 0, stream>>>(gbuf, ubuf, act_t);
    gemv_down_kernel<<<dim3(32, 8), 256, 0, stream>>>(act_t, down_w, out);
}

// Round 2
// 779.947 us; speedup vs baseline: 1.0251x; 1.0251x over previous
//
#include <hip/hip_runtime.h>
#include <math.h>

#define B_      32
#define H_      2048
#define NH_     32
#define NKV_    8
#define HD_     64
#define G_      4        // NH/NKV
#define INTER_  8192
#define NBLK_   256
#define BS_     16
#define NCHUNK_ 8
#define CHUNK_  512

// ---------------- ws layout (float offsets) ----------------
#define OFF_NORMED_T 0                    // [2048][32]
#define OFF_QKV_P    65536                // [16][32][3072]
#define OFF_QROPE    1638400              // [32][2048]
#define OFF_HT       1703936              // [2048][32]
#define OFF_ATTN_T   1769472              // [2048][32]
#define OFF_GU_P     1835008              // [8][32][16384]
#define OFF_ACT_T    6029312              // [8192][32]
#define OFF_O_P      6291456              // [16][32][2048]
#define OFF_D_P      7340032              // [32][32][2048]
#define OFF_OPART    9437184              // [8192][64]
#define OFF_MPART    9961472              // 8192
#define OFF_LPART    9969664              // 8192
// total 9977856 floats = ~40 MB

// ---------------- RMSNorm (x -> out_t transposed [H][B]) -------------------
__global__ __launch_bounds__(256) void rmsnorm_kernel(const float* __restrict__ xin,
                                                      const float* __restrict__ w,
                                                      float* __restrict__ out_t) {
    int b = blockIdx.x, tid = threadIdx.x;
    const float* xr = xin + (size_t)b * H_;
    float xv[8];
    float ss = 0.f;
#pragma unroll
    for (int j = 0; j < 8; ++j) {
        xv[j] = xr[tid + j * 256];
        ss += xv[j] * xv[j];
    }
#pragma unroll
    for (int off = 32; off >= 1; off >>= 1) ss += __shfl_xor(ss, off, 64);
    __shared__ float red[4];
    __shared__ float rbc;
    if ((tid & 63) == 0) red[tid >> 6] = ss;
    __syncthreads();
    if (tid == 0) rbc = rsqrtf((red[0] + red[1] + red[2] + red[3]) / (float)H_ + 1e-5f);
    __syncthreads();
    float r = rbc;
#pragma unroll
    for (int j = 0; j < 8; ++j) {
        int i = tid + j * 256;
        out_t[(size_t)i * B_ + b] = xv[j] * r * w[i];
    }
}

// ---------------- GEMV core: float4 weights, 4 cols x 32 batches ----------
// 256 threads: lane (tid&63) -> 4 consecutive cols; wave (tid>>6) -> k-split.
// Writes partial sums to part[blockIdx.y][b][Nout] after in-block LDS reduce.
__device__ __forceinline__ void gemv4_block(const float* __restrict__ xt,
                                            const float* __restrict__ W, int Nw,
                                            int wcol0, int rowsPerWave,
                                            float* __restrict__ part, int Nout,
                                            int outcol0) {
    int tid = threadIdx.x;
    int lane = tid & 63;
    int ks = tid >> 6;
    int k0 = (blockIdx.y * 4 + ks) * rowsPerWave;
    int wcol = wcol0 + lane * 4;

    float acc[4][B_];
#pragma unroll
    for (int c = 0; c < 4; ++c)
#pragma unroll
        for (int b = 0; b < B_; ++b) acc[c][b] = 0.f;

    const float* Wp = W + (size_t)k0 * Nw + wcol;
    const float* xp = xt + (size_t)k0 * B_;
#pragma unroll 2
    for (int k = 0; k < rowsPerWave; ++k) {
        float4 w4 = *(const float4*)(Wp + (size_t)k * Nw);
        const float* xr = xp + k * B_;   // wave-uniform address -> scalar loads
#pragma unroll
        for (int b = 0; b < B_; ++b) {
            float xv = xr[b];
            acc[0][b] = fmaf(w4.x, xv, acc[0][b]);
            acc[1][b] = fmaf(w4.y, xv, acc[1][b]);
            acc[2][b] = fmaf(w4.z, xv, acc[2][b]);
            acc[3][b] = fmaf(w4.w, xv, acc[3][b]);
        }
    }

    __shared__ float red[4][2][260];
    float* prow = part + (size_t)blockIdx.y * B_ * Nout;
    for (int b0 = 0; b0 < B_; b0 += 2) {
#pragma unroll
        for (int bi = 0; bi < 2; ++bi)
#pragma unroll
            for (int c = 0; c < 4; ++c)
                red[ks][bi][lane * 4 + c] = acc[c][b0 + bi];
        __syncthreads();
#pragma unroll
        for (int bi = 0; bi < 2; ++bi) {
            float s = red[0][bi][tid] + red[1][bi][tid] + red[2][bi][tid] + red[3][bi][tid];
            prow[(size_t)(b0 + bi) * Nout + outcol0 + tid] = s;
        }
        __syncthreads();
    }
}

// qkv fused: grid(12,16).  q cols 0..2047, k 2048..2559, v 2560..3071
__global__ __launch_bounds__(256, 2) void gemv_qkv_kernel(const float* __restrict__ xt,
                                                          const float* __restrict__ qw,
                                                          const float* __restrict__ kw,
                                                          const float* __restrict__ vw,
                                                          float* __restrict__ part) {
    int cb = blockIdx.x;
    if (cb < 8)       gemv4_block(xt, qw, 2048, cb * 256, 32, part, 3072, cb * 256);
    else if (cb < 10) gemv4_block(xt, kw, 512, (cb - 8) * 256, 32, part, 3072, cb * 256);
    else              gemv4_block(xt, vw, 512, (cb - 10) * 256, 32, part, 3072, cb * 256);
}

// o-proj: grid(8,16)
__global__ __launch_bounds__(256, 2) void gemv_o_kernel(const float* __restrict__ xt,
                                                        const float* __restrict__ W,
                                                        float* __restrict__ part) {
    gemv4_block(xt, W, 2048, blockIdx.x * 256, 32, part, 2048, blockIdx.x * 256);
}

// gate+up: grid(64,8). gate cols 0..8191, up 8192..16383
__global__ __launch_bounds__(256, 2) void gemv_gateup_kernel(const float* __restrict__ xt,
                                                             const float* __restrict__ gw,
                                                             const float* __restrict__ uw,
                                                             float* __restrict__ part) {
    int cb = blockIdx.x;
    if (cb < 32) gemv4_block(xt, gw, 8192, cb * 256, 64, part, 16384, cb * 256);
    else         gemv4_block(xt, uw, 8192, (cb - 32) * 256, 64, part, 16384, 8192 + (cb - 32) * 256);
}

// down: grid(8,32)
__global__ __launch_bounds__(256, 2) void gemv_down_kernel(const float* __restrict__ xt,
                                                           const float* __restrict__ W,
                                                           float* __restrict__ part) {
    gemv4_block(xt, W, 2048, blockIdx.x * 256, 64, part, 2048, blockIdx.x * 256);
}

// ---------------- qkv partial reduce + RoPE + paged cache write ------------
__global__ __launch_bounds__(256) void qkv_reduce_rope_kernel(const float* __restrict__ part,
                                                              const int* __restrict__ btab,
                                                              const int* __restrict__ seql,
                                                              float* __restrict__ qrope,
                                                              float* __restrict__ kc,
                                                              float* __restrict__ vc) {
    int b = blockIdx.x, tid = threadIdx.x;
    __shared__ float s[3072];
#pragma unroll
    for (int j = 0; j < 12; ++j) {
        int col = tid + j * 256;
        float a = 0.f;
#pragma unroll
        for (int y = 0; y < 16; ++y) a += part[((size_t)y * B_ + b) * 3072 + col];
        s[col] = a;
    }
    __syncthreads();
    int pos = seql[b];
    float fpos = (float)pos;
    const float LOG2T = 13.287712379549449f;  // log2(10000)
#pragma unroll
    for (int j = 0; j < 8; ++j) {
        int i = tid + j * 256;
        int d = i & 63, ii = d & 31;
        float ang = fpos * exp2f(-(float)(2 * ii) * (LOG2T / 64.f));
        float c = cosf(ang), sn = sinf(ang);
        float v1 = s[i], v2 = s[(d < 32) ? i + 32 : i - 32];
        qrope[(size_t)b * 2048 + i] = (d < 32) ? (v1 * c - v2 * sn) : (v1 * c + v2 * sn);
    }
    int blk = btab[b * NBLK_ + (pos >> 4)];
    size_t cbase = (size_t)(blk * BS_ + (pos & 15)) * NKV_ * HD_;
    for (int i = tid; i < NKV_ * HD_; i += 256) {
        int d = i & 63, ii = d & 31;
        float ang = fpos * exp2f(-(float)(2 * ii) * (LOG2T / 64.f));
        float c = cosf(ang), sn = sinf(ang);
        float v1 = s[2048 + i], v2 = s[2048 + ((d < 32) ? i + 32 : i - 32)];
        kc[cbase + i] = (d < 32) ? (v1 * c - v2 * sn) : (v1 * c + v2 * sn);
        vc[cbase + i] = s[2560 + i];
    }
}

// ---------------- flash-decode attention chunk (512 tokens) ---------------
// grid (NCHUNK, NKV, B), 256 threads
__global__ __launch_bounds__(256, 4) void attn_chunk_kernel(const float* __restrict__ qrope,
                                                            const float* __restrict__ kc,
                                                            const float* __restrict__ vc,
                                                            const int* __restrict__ btab,
                                                            const int* __restrict__ seqlens,
                                                            float* __restrict__ opart,
                                                            float* __restrict__ mpart,
                                                            float* __restrict__ lpart) {
    int cx = blockIdx.x, kv = blockIdx.y, b = blockIdx.z;
    int tid = threadIdx.x;
    int pos = seqlens[b];
    int c0 = cx * CHUNK_;
    int pidx = ((b * NKV_ + kv) * NCHUNK_ + cx) * G_;
    if (c0 > pos) {
        if (tid < G_) { mpart[pidx + tid] = -__builtin_inff(); lpart[pidx + tid] = 0.f; }
        return;
    }
    __shared__ float qlds[G_][HD_];
    __shared__ float slds[G_][CHUNK_];
    __shared__ float vt[32][HD_];
    __shared__ int btl[32];
    if (tid < 32) btl[tid] = btab[b * NBLK_ + (c0 >> 4) + tid];
    {
        int h = tid >> 6, d = tid & 63;
        qlds[h][d] = qrope[((size_t)b * NH_ + kv * G_ + h) * HD_ + d] * 0.125f; // 1/sqrt(64)
    }
    __syncthreads();

    // pass 1: QK^T, 16 tokens x 16 threads (float4 each), coalesced
    int grp = tid >> 4, ln = tid & 15;
    for (int tb = 0; tb < CHUNK_; tb += 16) {
        int tl = tb + grp;
        int t = c0 + tl;
        int blk = btl[tl >> 4];
        const float4 k4 = *(const float4*)(kc + ((size_t)(blk * BS_ + (t & 15)) * NKV_ + kv) * HD_ + ln * 4);
        bool valid = (t <= pos);
#pragma unroll
        for (int h = 0; h < G_; ++h) {
            const float4 q4 = *(const float4*)&qlds[h][ln * 4];
            float p = q4.x * k4.x + q4.y * k4.y + q4.z * k4.z + q4.w * k4.w;
#pragma unroll
            for (int off = 8; off >= 1; off >>= 1) p += __shfl_xor(p, off, 16);
            if (ln == 0) slds[h][tl] = valid ? p : -__builtin_inff();
        }
    }
    __syncthreads();

    // softmax per head (wave h -> head h)
    int h = tid >> 6, lane = tid & 63;
    float m = -__builtin_inff();
    for (int i = lane; i < CHUNK_; i += 64) m = fmaxf(m, slds[h][i]);
#pragma unroll
    for (int off = 32; off >= 1; off >>= 1) m = fmaxf(m, __shfl_xor(m, off, 64));
    float l = 0.f;
    for (int i = lane; i < CHUNK_; i += 64) {
        float p = expf(slds[h][i] - m);
        slds[h][i] = p;
        l += p;
    }
#pragma unroll
    for (int off = 32; off >= 1; off >>= 1) l += __shfl_xor(l, off, 64);
    if (lane == 0) { mpart[pidx + h] = m; lpart[pidx + h] = l; }
    __syncthreads();

    // pass 2: P.V with V staged in LDS, 32-token tiles
    int d = lane;
    float o = 0.f;
    int tmax = min(CHUNK_, pos + 1 - c0);
    for (int t0 = 0; t0 < tmax; t0 += 32) {
#pragma unroll
        for (int r = 0; r < 2; ++r) {
            int tl = t0 + r * 16 + (tid >> 4);
            int t = c0 + tl;
            int blk = btl[tl >> 4];
            // probs beyond tmax are exactly 0, so stale V values are harmless
            *(float4*)&vt[r * 16 + (tid >> 4)][(tid & 15) * 4] =
                *(const float4*)(vc + ((size_t)(blk * BS_ + (t & 15)) * NKV_ + kv) * HD_ + (tid & 15) * 4);
        }
        __syncthreads();
#pragma unroll 8
        for (int tl2 = 0; tl2 < 32; ++tl2)
            o = fmaf(slds[h][t0 + tl2], vt[tl2][d], o);
        __syncthreads();
    }
    opart[(size_t)(pidx + h) * HD_ + d] = o;
}

// ---------------- combine chunk partials ----------------------------------
__global__ __launch_bounds__(64) void attn_reduce_kernel(const float* __restrict__ opart,
                                                         const float* __restrict__ mpart,
                                                         const float* __restrict__ lpart,
                                                         float* __restrict__ attn_t) {
    int hq = blockIdx.x, b = blockIdx.y;
    int kv = hq >> 2, g = hq & 3;
    int lane = threadIdx.x;
    int base = ((b * NKV_ + kv) * NCHUNK_) * G_ + g;
    float mv[NCHUNK_], lv[NCHUNK_];
    float M = -__builtin_inff();
#pragma unroll
    for (int c = 0; c < NCHUNK_; ++c) {
        mv[c] = mpart[base + c * G_];
        lv[c] = lpart[base + c * G_];
        M = fmaxf(M, mv[c]);
    }
    float L = 0.f, o = 0.f;
#pragma unroll
    for (int c = 0; c < NCHUNK_; ++c) {
        if (lv[c] > 0.f) {
            float f = expf(mv[c] - M);
            L += lv[c] * f;
            o += f * opart[(size_t)(base + c * G_) * HD_ + lane];
        }
    }
    attn_t[(size_t)(hq * HD_ + lane) * B_ + b] = o / L;
}

// ---------------- o partial reduce + residual + RMSNorm2 + d_out copy ------
__global__ __launch_bounds__(256) void o_reduce_rms2_kernel(const float* __restrict__ part,
                                                            const float* __restrict__ x,
                                                            const float* __restrict__ w2,
                                                            float* __restrict__ out,
                                                            float* __restrict__ ht) {
    int b = blockIdx.x, tid = threadIdx.x;
    float v[8];
    float ss = 0.f;
#pragma unroll
    for (int j = 0; j < 8; ++j) {
        int col = tid + j * 256;
        float a = x[(size_t)b * H_ + col];
#pragma unroll
        for (int y = 0; y < 16; ++y) a += part[((size_t)y * B_ + b) * 2048 + col];
        v[j] = a;
        ss += a * a;
    }
#pragma unroll
    for (int off = 32; off >= 1; off >>= 1) ss += __shfl_xor(ss, off, 64);
    __shared__ float red[4];
    __shared__ float rbc;
    if ((tid & 63) == 0) red[tid >> 6] = ss;
    __syncthreads();
    if (tid == 0) rbc = rsqrtf((red[0] + red[1] + red[2] + red[3]) / (float)H_ + 1e-5f);
    __syncthreads();
    float r = rbc;
#pragma unroll
    for (int j = 0; j < 8; ++j) {
        int col = tid + j * 256;
        out[(size_t)b * H_ + col] = v[j];                     // x2 residual into d_out
        ht[(size_t)col * B_ + b] = v[j] * r * w2[col];        // normed, transposed
    }
}

// ---------------- gate/up partial reduce + SiLU + transpose ----------------
__global__ __launch_bounds__(256) void gu_reduce_silu_kernel(const float* __restrict__ part,
                                                             float* __restrict__ act_t) {
    int j0 = blockIdx.x * 64, tid = threadIdx.x;
    int jj = tid & 63, bq = tid >> 6;
    __shared__ float tile[64][33];
#pragma unroll
    for (int bb = 0; bb < 8; ++bb) {
        int b = bq * 8 + bb;
        float g = 0.f, u = 0.f;
#pragma unroll
        for (int y = 0; y < 8; ++y) {
            size_t base = ((size_t)y * B_ + b) * 16384 + j0 + jj;
            g += part[base];
            u += part[base + 8192];
        }
        tile[jj][b] = (g / (1.f + expf(-g))) * u;
    }
    __syncthreads();
#pragma unroll
    for (int r = 0; r < 8; ++r) {
        int j = r * 8 + (tid >> 5);
        int bc = tid & 31;
        act_t[(size_t)(j0 + j) * B_ + bc] = tile[j][bc];
    }
}

// ---------------- down partial reduce + residual ---------------------------
__global__ __launch_bounds__(256) void down_reduce_kernel(const float* __restrict__ part,
                                                          float* __restrict__ out) {
    int idx = blockIdx.x * 256 + threadIdx.x;   // 65536 outputs
    float a = out[idx];                         // x2 residual written earlier
#pragma unroll
    for (int y = 0; y < 32; ++y) a += part[(size_t)y * 65536 + idx];
    out[idx] = a;
}

// ---------------------------------------------------------------------------
extern "C" void kernel_launch(void* const* d_in, const int* in_sizes, int n_in,
                              void* d_out, int out_size, void* d_ws, size_t ws_size,
                              hipStream_t stream) {
    const float* x       = (const float*)d_in[0];
    float*       k_cache = (float*)d_in[1];
    float*       v_cache = (float*)d_in[2];
    const float* ln1_w   = (const float*)d_in[3];
    const float* q_w     = (const float*)d_in[4];
    const float* k_w     = (const float*)d_in[5];
    const float* v_w     = (const float*)d_in[6];
    const float* o_w     = (const float*)d_in[7];
    const float* ln2_w   = (const float*)d_in[8];
    const float* gate_w  = (const float*)d_in[9];
    const float* up_w    = (const float*)d_in[10];
    const float* down_w  = (const float*)d_in[11];
    const int*   btab    = (const int*)d_in[12];
    const int*   seql    = (const int*)d_in[13];
    float* out = (float*)d_out;

    float* ws = (float*)d_ws;
    float* normed_t = ws + OFF_NORMED_T;
    float* qkv_p    = ws + OFF_QKV_P;
    float* qrope    = ws + OFF_QROPE;
    float* ht       = ws + OFF_HT;
    float* attn_t   = ws + OFF_ATTN_T;
    float* gu_p     = ws + OFF_GU_P;
    float* act_t    = ws + OFF_ACT_T;
    float* o_p      = ws + OFF_O_P;
    float* d_p      = ws + OFF_D_P;
    float* opart    = ws + OFF_OPART;
    float* mpart    = ws + OFF_MPART;
    float* lpart    = ws + OFF_LPART;

    rmsnorm_kernel<<<32, 256, 0, stream>>>(x, ln1_w, normed_t);
    gemv_qkv_kernel<<<dim3(12, 16), 256, 0, stream>>>(normed_t, q_w, k_w, v_w, qkv_p);
    qkv_reduce_rope_kernel<<<32, 256, 0, stream>>>(qkv_p, btab, seql, qrope, k_cache, v_cache);
    attn_chunk_kernel<<<dim3(NCHUNK_, NKV_, B_), 256, 0, stream>>>(qrope, k_cache, v_cache,
                                                                   btab, seql, opart, mpart, lpart);
    attn_reduce_kernel<<<dim3(NH_, B_), 64, 0, stream>>>(opart, mpart, lpart, attn_t);
    gemv_o_kernel<<<dim3(8, 16), 256, 0, stream>>>(attn_t, o_w, o_p);
    o_reduce_rms2_kernel<<<32, 256, 0, stream>>>(o_p, x, ln2_w, out, ht);
    gemv_gateup_kernel<<<dim3(64, 8), 256, 0, stream>>>(ht, gate_w, up_w, gu_p);
    gu_reduce_silu_kernel<<<128, 256, 0, stream>>>(gu_p, act_t);
    gemv_down_kernel<<<dim3(8, 32), 256, 0, stream>>>(act_t, down_w, d_p);
    down_reduce_kernel<<<256, 256, 0, stream>>>(d_p, out);
}